// Round 1
// baseline (83.122 us; speedup 1.0000x reference)
//
#include <hip/hip_runtime.h>
#include <math.h>

#define TB 256
#define S_LEN 8000
#define B_N 128
#define NCHUNK 32   // ceil(8000/256) = 32 (covers 8192 rows, tail guarded)

// ---------------- device helpers ----------------

__device__ __forceinline__ void compute_ln(const float* __restrict__ xs, const float* __restrict__ ps,
                                           const float* __restrict__ lg, const float* __restrict__ lb,
                                           float* y) {
  float v[9];
  float m = 0.f;
#pragma unroll
  for (int j = 0; j < 9; ++j) { v[j] = xs[j] + ps[j]; m += v[j]; }
  m *= (1.f / 9.f);
  float var = 0.f;
#pragma unroll
  for (int j = 0; j < 9; ++j) { float d = v[j] - m; var += d * d; }
  var *= (1.f / 9.f);
  float rs = rsqrtf(var + 1e-6f);
#pragma unroll
  for (int j = 0; j < 9; ++j) y[j] = (v[j] - m) * rs * lg[j] + lb[j];
}

__device__ __forceinline__ void matvec89(const float* __restrict__ W, const float* __restrict__ bias,
                                         const float* __restrict__ y, float* out) {
#pragma unroll
  for (int i = 0; i < 8; ++i) {
    float a = bias[i];
#pragma unroll
    for (int j = 0; j < 9; ++j) a += W[i * 9 + j] * y[j];
    out[i] = a;
  }
}

// scale for one head: cosine_sim(v, unbind(bind, q)) + (1-mask)*-1e9
__device__ __forceinline__ float head_scale(const float* q, const float* v, const float* bindS,
                                            int h, float maskv) {
  float q0 = q[2 * h], q1 = q[2 * h + 1];
  float v0 = v[2 * h], v1 = v[2 * h + 1];
  float B0 = bindS[2 * h], B1 = bindS[2 * h + 1];
  // HD=2 circular "unbinding" == circular conv (real 2-pt FFT is self-conjugate)
  float vp0 = B0 * q0 + B1 * q1;
  float vp1 = B0 * q1 + B1 * q0;
  float num = v0 * vp0 + v1 * vp1;
  float na = fmaxf(sqrtf(v0 * v0 + v1 * v1), 1e-8f);
  float nb = fmaxf(sqrtf(vp0 * vp0 + vp1 * vp1), 1e-8f);
  float sc = num / (na * nb);
  sc += (1.f - maskv) * (-1e9f);
  return sc;
}

// ---------------- kernel A: bind partials ----------------
// grid (NCHUNK, B_N), block TB. bindPartial[b][chunk][8]
__global__ __launch_bounds__(TB) void k_bind_partial(
    const float* __restrict__ x, const float* __restrict__ pos,
    const float* __restrict__ lng, const float* __restrict__ lnb,
    const float* __restrict__ Wk, const float* __restrict__ bk,
    const float* __restrict__ Wv, const float* __restrict__ bv,
    float* __restrict__ bindPartial) {
  __shared__ float xs[TB * 9];
  __shared__ float ps[TB * 9];
  __shared__ float wkS[72], wvS[72], bkS[8], bvS[8], lgS[9], lbS[9];
  __shared__ float red[4 * 8];

  const int b = blockIdx.y, cx = blockIdx.x, tid = threadIdx.x;
  const int s0 = cx * TB;
  const int nrow = min(TB, S_LEN - s0);
  const int nelem = nrow * 9;
  const float* xbase = x + ((size_t)b * S_LEN + s0) * 9;
  const float* pbase = pos + (size_t)s0 * 9;
  for (int i = tid; i < nelem; i += TB) { xs[i] = xbase[i]; ps[i] = pbase[i]; }
  if (tid < 72) { wkS[tid] = Wk[tid]; wvS[tid] = Wv[tid]; }
  if (tid < 8)  { bkS[tid] = bk[tid]; bvS[tid] = bv[tid]; }
  if (tid < 9)  { lgS[tid] = lng[tid]; lbS[tid] = lnb[tid]; }
  __syncthreads();

  float acc[8];
#pragma unroll
  for (int i = 0; i < 8; ++i) acc[i] = 0.f;

  if (tid < nrow) {
    float y[9];
    compute_ln(&xs[tid * 9], &ps[tid * 9], lgS, lbS, y);
    float kk[8], vv[8];
    matvec89(wkS, bkS, y, kk);
    matvec89(wvS, bvS, y, vv);
#pragma unroll
    for (int h = 0; h < 4; ++h) {
      float k0 = kk[2 * h], k1 = kk[2 * h + 1];
      float v0 = vv[2 * h], v1 = vv[2 * h + 1];
      acc[2 * h]     = k0 * v0 + k1 * v1;  // circular conv elem 0
      acc[2 * h + 1] = k0 * v1 + k1 * v0;  // circular conv elem 1
    }
  }

  // wave reduce (64-wide) then cross-wave via LDS
#pragma unroll
  for (int i = 0; i < 8; ++i) {
#pragma unroll
    for (int off = 32; off > 0; off >>= 1) acc[i] += __shfl_down(acc[i], off, 64);
  }
  const int wave = tid >> 6, lane = tid & 63;
  if (lane == 0) {
#pragma unroll
    for (int i = 0; i < 8; ++i) red[wave * 8 + i] = acc[i];
  }
  __syncthreads();
  if (tid < 8) {
    float s = red[tid] + red[8 + tid] + red[16 + tid] + red[24 + tid];
    bindPartial[((size_t)b * NCHUNK + cx) * 8 + tid] = s;
  }
}

// ---------------- kernel B: reduce bind partials ----------------
__global__ void k_bind_reduce(const float* __restrict__ bp, float* __restrict__ bind) {
  int i = blockIdx.x * TB + threadIdx.x;  // 1024 = 128*8
  if (i < B_N * 8) {
    int b = i >> 3, c = i & 7;
    float s = 0.f;
    for (int j = 0; j < NCHUNK; ++j) s += bp[((size_t)b * NCHUNK + j) * 8 + c];
    bind[i] = s;
  }
}

// ---------------- kernel C: softmax denominator partials ----------------
// sumPartial[b][chunk][4]
__global__ __launch_bounds__(TB) void k_sum_partial(
    const float* __restrict__ x, const float* __restrict__ pos, const float* __restrict__ mask,
    const float* __restrict__ lng, const float* __restrict__ lnb,
    const float* __restrict__ Wq, const float* __restrict__ bq,
    const float* __restrict__ Wv, const float* __restrict__ bv,
    const float* __restrict__ bind, float* __restrict__ sumPartial) {
  __shared__ float xs[TB * 9];
  __shared__ float ps[TB * 9];
  __shared__ float wqS[72], wvS[72], bqS[8], bvS[8], lgS[9], lbS[9], bindS[8];
  __shared__ float red[4 * 4];

  const int b = blockIdx.y, cx = blockIdx.x, tid = threadIdx.x;
  const int s0 = cx * TB;
  const int nrow = min(TB, S_LEN - s0);
  const int nelem = nrow * 9;
  const float* xbase = x + ((size_t)b * S_LEN + s0) * 9;
  const float* pbase = pos + (size_t)s0 * 9;
  for (int i = tid; i < nelem; i += TB) { xs[i] = xbase[i]; ps[i] = pbase[i]; }
  if (tid < 72) { wqS[tid] = Wq[tid]; wvS[tid] = Wv[tid]; }
  if (tid < 8)  { bqS[tid] = bq[tid]; bvS[tid] = bv[tid]; bindS[tid] = bind[b * 8 + tid]; }
  if (tid < 9)  { lgS[tid] = lng[tid]; lbS[tid] = lnb[tid]; }
  __syncthreads();

  float e[4];
#pragma unroll
  for (int h = 0; h < 4; ++h) e[h] = 0.f;

  if (tid < nrow) {
    const int s = s0 + tid;
    float y[9];
    compute_ln(&xs[tid * 9], &ps[tid * 9], lgS, lbS, y);
    float qq[8], vv[8];
    matvec89(wqS, bqS, y, qq);
    matvec89(wvS, bvS, y, vv);
#pragma unroll
    for (int h = 0; h < 4; ++h) {
      float m = mask[((size_t)(b * 4 + h)) * S_LEN + s];
      float sc = head_scale(qq, vv, bindS, h, m);
      e[h] = expf(sc);  // |scale| <= 1 (cosine sim), no max-subtraction needed
    }
  }

#pragma unroll
  for (int h = 0; h < 4; ++h) {
#pragma unroll
    for (int off = 32; off > 0; off >>= 1) e[h] += __shfl_down(e[h], off, 64);
  }
  const int wave = tid >> 6, lane = tid & 63;
  if (lane == 0) {
#pragma unroll
    for (int h = 0; h < 4; ++h) red[wave * 4 + h] = e[h];
  }
  __syncthreads();
  if (tid < 4) {
    float s = red[tid] + red[4 + tid] + red[8 + tid] + red[12 + tid];
    sumPartial[((size_t)b * NCHUNK + cx) * 4 + tid] = s;
  }
}

// ---------------- kernel D: reduce denom partials -> 1/D ----------------
__global__ void k_sum_reduce(const float* __restrict__ sp, float* __restrict__ invD) {
  int i = blockIdx.x * TB + threadIdx.x;  // 512 = 128*4
  if (i < B_N * 4) {
    int b = i >> 2, h = i & 3;
    float s = 0.f;
    for (int j = 0; j < NCHUNK; ++j) s += sp[((size_t)b * NCHUNK + j) * 4 + h];
    invD[i] = 1.f / s;
  }
}

// ---------------- kernel E: final output ----------------
__global__ __launch_bounds__(TB) void k_output(
    const float* __restrict__ x, const float* __restrict__ pos, const float* __restrict__ mask,
    const float* __restrict__ lng, const float* __restrict__ lnb,
    const float* __restrict__ Wq, const float* __restrict__ bq,
    const float* __restrict__ Wv, const float* __restrict__ bv,
    const float* __restrict__ W2, const float* __restrict__ b2,
    const float* __restrict__ Wo, const float* __restrict__ bo,
    const float* __restrict__ bind, const float* __restrict__ invD,
    float* __restrict__ out) {
  __shared__ float xs[TB * 9];
  __shared__ float ps[TB * 9];
  __shared__ float wqS[72], wvS[72], bqS[8], bvS[8];
  __shared__ float w2S[72], b2S[9], woS[9], lgS[9], lbS[9], bindS[8], invDS[4];
  __shared__ float boS;

  const int b = blockIdx.y, cx = blockIdx.x, tid = threadIdx.x;
  const int s0 = cx * TB;
  const int nrow = min(TB, S_LEN - s0);
  const int nelem = nrow * 9;
  const float* xbase = x + ((size_t)b * S_LEN + s0) * 9;
  const float* pbase = pos + (size_t)s0 * 9;
  for (int i = tid; i < nelem; i += TB) { xs[i] = xbase[i]; ps[i] = pbase[i]; }
  if (tid < 72) { wqS[tid] = Wq[tid]; wvS[tid] = Wv[tid]; w2S[tid] = W2[tid]; }
  if (tid < 8)  { bqS[tid] = bq[tid]; bvS[tid] = bv[tid]; bindS[tid] = bind[b * 8 + tid]; }
  if (tid < 9)  { lgS[tid] = lng[tid]; lbS[tid] = lnb[tid]; b2S[tid] = b2[tid]; woS[tid] = Wo[tid]; }
  if (tid < 4)  { invDS[tid] = invD[b * 4 + tid]; }
  if (tid == 0) { boS = bo[0]; }
  __syncthreads();

  if (tid < nrow) {
    const int s = s0 + tid;
    float y[9];
    compute_ln(&xs[tid * 9], &ps[tid * 9], lgS, lbS, y);
    float qq[8], vv[8];
    matvec89(wqS, bqS, y, qq);
    matvec89(wvS, bvS, y, vv);

    float attn[8];
#pragma unroll
    for (int h = 0; h < 4; ++h) {
      float m = mask[((size_t)(b * 4 + h)) * S_LEN + s];
      float sc = head_scale(qq, vv, bindS, h, m);
      float w = expf(sc) * invDS[h];
      attn[2 * h]     = w * vv[2 * h];
      attn[2 * h + 1] = w * vv[2 * h + 1];
    }

    // t = attn @ W2.T + b2  (W2 is [9][8]); gelu exact; residual +y; dot Wo
    float o = boS;
#pragma unroll
    for (int i = 0; i < 9; ++i) {
      float t = b2S[i];
#pragma unroll
      for (int j = 0; j < 8; ++j) t += w2S[i * 8 + j] * attn[j];
      float g = 0.5f * t * (1.f + erff(t * 0.70710678118654752f));
      o += woS[i] * (g + y[i]);
    }
    out[(size_t)b * S_LEN + s] = o;
  }
}

// ---------------- launch ----------------

extern "C" void kernel_launch(void* const* d_in, const int* in_sizes, int n_in,
                              void* d_out, int out_size, void* d_ws, size_t ws_size,
                              hipStream_t stream) {
  const float* x    = (const float*)d_in[0];
  const float* mask = (const float*)d_in[1];
  const float* pos  = (const float*)d_in[2];
  const float* lng  = (const float*)d_in[3];
  const float* lnb  = (const float*)d_in[4];
  const float* Wq   = (const float*)d_in[5];
  const float* bq   = (const float*)d_in[6];
  const float* Wk   = (const float*)d_in[7];
  const float* bk   = (const float*)d_in[8];
  const float* Wv   = (const float*)d_in[9];
  const float* bv   = (const float*)d_in[10];
  // d_in[11] = W1, d_in[12] = b1  (dead code in reference)
  const float* W2   = (const float*)d_in[13];
  const float* b2   = (const float*)d_in[14];
  const float* Wo   = (const float*)d_in[15];
  const float* bo   = (const float*)d_in[16];
  float* out = (float*)d_out;

  float* ws = (float*)d_ws;
  float* bindPartial = ws;                   // 128*32*8 = 32768
  float* bind        = ws + 32768;           // 1024
  float* sumPartial  = ws + 32768 + 1024;    // 128*32*4 = 16384
  float* invD        = ws + 32768 + 1024 + 16384;  // 512

  dim3 grid(NCHUNK, B_N);
  k_bind_partial<<<grid, TB, 0, stream>>>(x, pos, lng, lnb, Wk, bk, Wv, bv, bindPartial);
  k_bind_reduce<<<4, TB, 0, stream>>>(bindPartial, bind);
  k_sum_partial<<<grid, TB, 0, stream>>>(x, pos, mask, lng, lnb, Wq, bq, Wv, bv, bind, sumPartial);
  k_sum_reduce<<<2, TB, 0, stream>>>(sumPartial, invD);
  k_output<<<grid, TB, 0, stream>>>(x, pos, mask, lng, lnb, Wq, bq, Wv, bv, W2, b2, Wo, bo,
                                    bind, invD, out);
}

// Round 3
// 70.782 us; speedup vs baseline: 1.1743x; 1.1743x over previous
//
#include <hip/hip_runtime.h>
#include <math.h>

#define TB 256
#define S_LEN 8000
#define B_N 128
#define NCHUNK 32   // ceil(8000/256)

// ---------------- device helpers ----------------

__device__ __forceinline__ void compute_ln(const float* __restrict__ xp,
                                           const float* __restrict__ lg, const float* __restrict__ lb,
                                           float* y) {
  float v[9];
  float m = 0.f;
#pragma unroll
  for (int j = 0; j < 9; ++j) { v[j] = xp[j]; m += v[j]; }
  m *= (1.f / 9.f);
  float var = 0.f;
#pragma unroll
  for (int j = 0; j < 9; ++j) { float d = v[j] - m; var += d * d; }
  var *= (1.f / 9.f);
  float rs = rsqrtf(var + 1e-6f);
#pragma unroll
  for (int j = 0; j < 9; ++j) y[j] = (v[j] - m) * rs * lg[j] + lb[j];
}

__device__ __forceinline__ void matvec89(const float* __restrict__ W, const float* __restrict__ bias,
                                         const float* __restrict__ y, float* out) {
#pragma unroll
  for (int i = 0; i < 8; ++i) {
    float a = bias[i];
#pragma unroll
    for (int j = 0; j < 9; ++j) a += W[i * 9 + j] * y[j];
    out[i] = a;
  }
}

__device__ __forceinline__ float head_scale(const float* q, const float* v, const float* bindS,
                                            int h, float maskv) {
  float q0 = q[2 * h], q1 = q[2 * h + 1];
  float v0 = v[2 * h], v1 = v[2 * h + 1];
  float B0 = bindS[2 * h], B1 = bindS[2 * h + 1];
  // HD=2: real 2-pt FFT self-conjugate -> unbinding == circular conv
  float vp0 = B0 * q0 + B1 * q1;
  float vp1 = B0 * q1 + B1 * q0;
  float num = v0 * vp0 + v1 * vp1;
  float na = fmaxf(sqrtf(v0 * v0 + v1 * v1), 1e-8f);
  float nb = fmaxf(sqrtf(vp0 * vp0 + vp1 * vp1), 1e-8f);
  float sc = num / (na * nb);
  sc += (1.f - maskv) * (-1e9f);
  return sc;
}

// stage x+pos tile into LDS as float4 (block base is 16B aligned: 36B*256 rows)
__device__ __forceinline__ void stage_x(const float* __restrict__ x, const float* __restrict__ pos,
                                        int b, int s0, int nrow, float4* xs4, int tid) {
  const int n4 = (nrow * 9) >> 2;  // nrow*9 divisible by 4 for nrow=256 and 64 (tail 8000-31*256=64)
  const float4* xb4 = (const float4*)(x + ((size_t)b * S_LEN + s0) * 9);
  const float4* pb4 = (const float4*)(pos + (size_t)s0 * 9);
  for (int i = tid; i < n4; i += TB) {
    float4 a = xb4[i], p = pb4[i];
    xs4[i] = make_float4(a.x + p.x, a.y + p.y, a.z + p.z, a.w + p.w);
  }
}

// ---------------- kernel 1: bind partials ----------------
__global__ __launch_bounds__(TB) void k_bind(
    const float* __restrict__ x, const float* __restrict__ pos,
    const float* __restrict__ lng, const float* __restrict__ lnb,
    const float* __restrict__ Wk, const float* __restrict__ bk,
    const float* __restrict__ Wv, const float* __restrict__ bv,
    float* __restrict__ bindPartial) {
  __shared__ float4 xs4[TB * 9 / 4];
  __shared__ float wkS[72], wvS[72], bkS[8], bvS[8], lgS[9], lbS[9];
  __shared__ float red[4 * 8];
  float* xs = (float*)xs4;

  const int b = blockIdx.y, cx = blockIdx.x, tid = threadIdx.x;
  const int s0 = cx * TB;
  const int nrow = min(TB, S_LEN - s0);

  stage_x(x, pos, b, s0, nrow, xs4, tid);
  if (tid < 72) { wkS[tid] = Wk[tid]; wvS[tid] = Wv[tid]; }
  if (tid < 8)  { bkS[tid] = bk[tid]; bvS[tid] = bv[tid]; }
  if (tid < 9)  { lgS[tid] = lng[tid]; lbS[tid] = lnb[tid]; }
  __syncthreads();

  float acc[8];
#pragma unroll
  for (int i = 0; i < 8; ++i) acc[i] = 0.f;
  if (tid < nrow) {
    float y[9];
    compute_ln(&xs[tid * 9], lgS, lbS, y);
    float kk[8], vv[8];
    matvec89(wkS, bkS, y, kk);
    matvec89(wvS, bvS, y, vv);
#pragma unroll
    for (int h = 0; h < 4; ++h) {
      float k0 = kk[2 * h], k1 = kk[2 * h + 1];
      float v0 = vv[2 * h], v1 = vv[2 * h + 1];
      acc[2 * h]     = k0 * v0 + k1 * v1;
      acc[2 * h + 1] = k0 * v1 + k1 * v0;
    }
  }
#pragma unroll
  for (int i = 0; i < 8; ++i) {
#pragma unroll
    for (int off = 32; off > 0; off >>= 1) acc[i] += __shfl_down(acc[i], off, 64);
  }
  const int wave = tid >> 6, lane = tid & 63;
  if (lane == 0) {
#pragma unroll
    for (int i = 0; i < 8; ++i) red[wave * 8 + i] = acc[i];
  }
  __syncthreads();
  if (tid < 8) {
    bindPartial[((size_t)b * NCHUNK + cx) * 8 + tid] =
        red[tid] + red[8 + tid] + red[16 + tid] + red[24 + tid];
  }
}

// ---------------- kernel 2: ew numerators + denom partials ----------------
__global__ __launch_bounds__(TB) void k_scale(
    const float* __restrict__ x, const float* __restrict__ pos, const float* __restrict__ mask,
    const float* __restrict__ lng, const float* __restrict__ lnb,
    const float* __restrict__ Wq, const float* __restrict__ bq,
    const float* __restrict__ Wv, const float* __restrict__ bv,
    const float* __restrict__ bindPartial,
    float4* __restrict__ ew, float* __restrict__ sumPartial) {
  __shared__ float4 xs4[TB * 9 / 4];
  __shared__ float wqS[72], wvS[72], bqS[8], bvS[8], lgS[9], lbS[9];
  __shared__ float bpS[TB];       // 32 chunks x 8 comps
  __shared__ float bindS[8];
  __shared__ float red[4 * 4];
  float* xs = (float*)xs4;

  const int b = blockIdx.y, cx = blockIdx.x, tid = threadIdx.x;
  const int s0 = cx * TB;
  const int nrow = min(TB, S_LEN - s0);

  stage_x(x, pos, b, s0, nrow, xs4, tid);
  bpS[tid] = bindPartial[(size_t)b * NCHUNK * 8 + tid];  // all 256 partial words, parallel
  if (tid < 72) { wqS[tid] = Wq[tid]; wvS[tid] = Wv[tid]; }
  if (tid < 8)  { bqS[tid] = bq[tid]; bvS[tid] = bv[tid]; }
  if (tid < 9)  { lgS[tid] = lng[tid]; lbS[tid] = lnb[tid]; }
  __syncthreads();
  if (tid < 8) {
    float s = 0.f;
#pragma unroll
    for (int j = 0; j < NCHUNK; ++j) s += bpS[j * 8 + tid];
    bindS[tid] = s;
  }
  __syncthreads();

  float e[4];
#pragma unroll
  for (int h = 0; h < 4; ++h) e[h] = 0.f;
  if (tid < nrow) {
    const int s = s0 + tid;
    float y[9];
    compute_ln(&xs[tid * 9], lgS, lbS, y);
    float qq[8], vv[8];
    matvec89(wqS, bqS, y, qq);
    matvec89(wvS, bvS, y, vv);
#pragma unroll
    for (int h = 0; h < 4; ++h) {
      float m = mask[((size_t)(b * 4 + h)) * S_LEN + s];
      e[h] = expf(head_scale(qq, vv, bindS, h, m));  // |cos sim|<=1: no max-sub
    }
    ew[(size_t)b * S_LEN + s] = make_float4(e[0], e[1], e[2], e[3]);
  }
#pragma unroll
  for (int h = 0; h < 4; ++h) {
#pragma unroll
    for (int off = 32; off > 0; off >>= 1) e[h] += __shfl_down(e[h], off, 64);
  }
  const int wave = tid >> 6, lane = tid & 63;
  if (lane == 0) {
#pragma unroll
    for (int h = 0; h < 4; ++h) red[wave * 4 + h] = e[h];
  }
  __syncthreads();
  if (tid < 4) {
    sumPartial[((size_t)b * NCHUNK + cx) * 4 + tid] =
        red[tid] + red[4 + tid] + red[8 + tid] + red[12 + tid];
  }
}

// ---------------- kernel 3: output ----------------
__global__ __launch_bounds__(TB) void k_out(
    const float* __restrict__ x, const float* __restrict__ pos,
    const float* __restrict__ lng, const float* __restrict__ lnb,
    const float* __restrict__ Wv, const float* __restrict__ bv,
    const float* __restrict__ W2, const float* __restrict__ b2,
    const float* __restrict__ Wo, const float* __restrict__ bo,
    const float4* __restrict__ ew, const float* __restrict__ sumPartial,
    float* __restrict__ out) {
  __shared__ float4 xs4[TB * 9 / 4];
  __shared__ float wvS[72], w2S[72], bvS[8], b2S[9], woS[9], lgS[9], lbS[9];
  __shared__ float spS[128];      // 32 chunks x 4 heads
  __shared__ float invDS[4];
  __shared__ float boS;
  float* xs = (float*)xs4;

  const int b = blockIdx.y, cx = blockIdx.x, tid = threadIdx.x;
  const int s0 = cx * TB;
  const int nrow = min(TB, S_LEN - s0);

  stage_x(x, pos, b, s0, nrow, xs4, tid);
  if (tid < 128) spS[tid] = sumPartial[(size_t)b * NCHUNK * 4 + tid];
  if (tid < 72) { wvS[tid] = Wv[tid]; w2S[tid] = W2[tid]; }
  if (tid < 8)  { bvS[tid] = bv[tid]; }
  if (tid < 9)  { lgS[tid] = lng[tid]; lbS[tid] = lnb[tid]; b2S[tid] = b2[tid]; woS[tid] = Wo[tid]; }
  if (tid == 0) { boS = bo[0]; }
  __syncthreads();
  if (tid < 4) {
    float s = 0.f;
#pragma unroll
    for (int j = 0; j < NCHUNK; ++j) s += spS[j * 4 + tid];
    invDS[tid] = 1.f / s;
  }
  __syncthreads();

  if (tid < nrow) {
    const int s = s0 + tid;
    float y[9];
    compute_ln(&xs[tid * 9], lgS, lbS, y);
    float vv[8];
    matvec89(wvS, bvS, y, vv);

    float4 e4 = ew[(size_t)b * S_LEN + s];
    float w0 = e4.x * invDS[0], w1 = e4.y * invDS[1], w2 = e4.z * invDS[2], w3 = e4.w * invDS[3];
    float attn[8] = {w0 * vv[0], w0 * vv[1], w1 * vv[2], w1 * vv[3],
                     w2 * vv[4], w2 * vv[5], w3 * vv[6], w3 * vv[7]};

    float o = boS;
#pragma unroll
    for (int i = 0; i < 9; ++i) {
      float t = b2S[i];
#pragma unroll
      for (int j = 0; j < 8; ++j) t += w2S[i * 8 + j] * attn[j];
      float g = 0.5f * t * (1.f + erff(t * 0.70710678118654752f));
      o += woS[i] * (g + y[i]);
    }
    out[(size_t)b * S_LEN + s] = o;
  }
}

// ---------------- launch ----------------

extern "C" void kernel_launch(void* const* d_in, const int* in_sizes, int n_in,
                              void* d_out, int out_size, void* d_ws, size_t ws_size,
                              hipStream_t stream) {
  const float* x    = (const float*)d_in[0];
  const float* mask = (const float*)d_in[1];
  const float* pos  = (const float*)d_in[2];
  const float* lng  = (const float*)d_in[3];
  const float* lnb  = (const float*)d_in[4];
  const float* Wq   = (const float*)d_in[5];
  const float* bq   = (const float*)d_in[6];
  const float* Wk   = (const float*)d_in[7];
  const float* bk   = (const float*)d_in[8];
  const float* Wv   = (const float*)d_in[9];
  const float* bv   = (const float*)d_in[10];
  // d_in[11] = W1, d_in[12] = b1  (dead in reference)
  const float* W2   = (const float*)d_in[13];
  const float* b2   = (const float*)d_in[14];
  const float* Wo   = (const float*)d_in[15];
  const float* bo   = (const float*)d_in[16];
  float* out = (float*)d_out;

  float* ws = (float*)d_ws;
  float*  bindPartial = ws;                    // 128*32*8  = 32768 floats
  float*  sumPartial  = ws + 32768;            // 128*32*4  = 16384 floats
  float4* ew          = (float4*)(ws + 32768 + 16384);  // 128*8000 float4 = 16.4 MB

  dim3 grid(NCHUNK, B_N);
  k_bind<<<grid, TB, 0, stream>>>(x, pos, lng, lnb, Wk, bk, Wv, bv, bindPartial);
  k_scale<<<grid, TB, 0, stream>>>(x, pos, mask, lng, lnb, Wq, bq, Wv, bv,
                                   bindPartial, ew, sumPartial);
  k_out<<<grid, TB, 0, stream>>>(x, pos, lng, lnb, Wv, bv, W2, b2, Wo, bo,
                                 ew, sumPartial, out);
}